// Round 1
// baseline (62397.650 us; speedup 1.0000x reference)
//
// SCN-LSTM persistent-kernel implementation for MI355X (gfx950).
//
// Design (round 1):
//  - Persistent cooperative-style kernel, 256 blocks x 256 threads (1 block/CU),
//    hand-rolled grid barrier (agent-scope atomics) in d_ws.
//  - Layer-skewed pipeline: tick tau does layer0 step tau and layer1 step tau-1
//    => 2 grid barriers per tick, 2*(T+1) total.
//  - Phase A: P0 = (x_t @ Wc0) * tb0 ; P1 = (h0 @ Uc0) * ub0 ;
//             P2 = (h1 @ Uc1) * ub1 ; P3 = (h0 @ Wc1) * tb1   (all bf16 MFMA)
//  - Phase B: layer0 gates = sigmoid(P0@Wa0 + P1@Ua0 + b0) -> c0,h0 update;
//             layer1 gates = sigmoid(P3@Wa1 + P2@Ua1 + b1) -> c1,h1, out[t].
//  - Weights pre-transposed to (g, n, k) bf16; tag projections precomputed.
#include <hip/hip_runtime.h>

typedef unsigned short u16;
typedef __attribute__((ext_vector_type(8))) short s16x8;
typedef __attribute__((ext_vector_type(4))) float f32x4;
typedef __attribute__((ext_vector_type(4))) float float4v;

#define T_ 1024
#define OUT_HST 33554432   // 64*1024*512
#define OUT_CST 33619968   // + 64*2*512

// workspace byte offsets
#define WT_BYTES   (1u << 21)                // 2MB per transposed weight tensor (4x512x512 bf16)
#define OFF_SC     (8u * WT_BYTES)           // 16,777,216 : tb0, ub0, ub1, tb1 (4x4x64x512 f32)
#define OFF_P      (OFF_SC + 2097152u)       // 18,874,368 : P0..P3 (4 x 4x64x512 bf16)
#define OFF_HST    (OFF_P + 1048576u)        // 19,922,944 : h state, 2 layers, bf16
#define OFF_CSTATE (OFF_HST + 131072u)       // 20,054,016 : c state, 2 layers, f32
#define OFF_BAR    (OFF_CSTATE + 262144u)    // 20,316,160 : barrier counters

__device__ __forceinline__ u16 f2bf(float f) {
  union { float f; unsigned u; } v; v.f = f;
  return (u16)((v.u + 0x7FFFu + ((v.u >> 16) & 1u)) >> 16);
}

__device__ __forceinline__ s16x8 cvt8(const float* p) {
  float4v a = *(const float4v*)p;
  float4v b = *(const float4v*)(p + 4);
  s16x8 r;
  r[0] = (short)f2bf(a[0]); r[1] = (short)f2bf(a[1]);
  r[2] = (short)f2bf(a[2]); r[3] = (short)f2bf(a[3]);
  r[4] = (short)f2bf(b[0]); r[5] = (short)f2bf(b[1]);
  r[6] = (short)f2bf(b[2]); r[7] = (short)f2bf(b[3]);
  return r;
}

__device__ __forceinline__ f32x4 mfma_bf16(s16x8 a, s16x8 b, f32x4 c) {
  return __builtin_amdgcn_mfma_f32_16x16x32_bf16(a, b, c, 0, 0, 0);
}

// ---------------- prep kernels ----------------

struct SrcPtrs { const float* p[8]; };

// Transpose 8 weight tensors (4,512,512) f32 [g][k][n] -> (4,512,512) bf16 [g][n][k]
__global__ void prep_transpose(SrcPtrs s, unsigned char* ws) {
  __shared__ float tb[64][65];
  int bid = blockIdx.x, tid = threadIdx.x;
  int ten = bid >> 8, g = (bid >> 6) & 3, tile = bid & 63;
  int tk = (tile >> 3) << 6, tn = (tile & 7) << 6;
  const float* src = s.p[ten] + ((size_t)g << 18);
  u16* dst = (u16*)(ws + (size_t)ten * WT_BYTES) + ((size_t)g << 18);
  int c = tid & 63, i0 = tid >> 6;
  for (int i = i0; i < 64; i += 4)
    tb[i][c] = src[(size_t)(tk + i) * 512 + tn + c];
  __syncthreads();
  for (int i = i0; i < 64; i += 4)
    dst[(size_t)(tn + i) * 512 + tk + c] = f2bf(tb[c][i]);
}

// SC[m][g][b][f] = sum_k tag[b][k] * W_m[g][k][f], K=300.  m: tb0, ub0, ub1, tb1
__global__ void prep_scales(const float* tag, const float* w0, const float* w1,
                            const float* w2, const float* w3, unsigned char* ws) {
  int t = blockIdx.x * 256 + threadIdx.x;
  int f = t & 511, b = (t >> 9) & 63, g = (t >> 15) & 3, m = t >> 17;
  const float* W = (m == 0) ? w0 : (m == 1) ? w1 : (m == 2) ? w2 : w3;
  const float* tg = tag + b * 300;
  const float* wp = W + (size_t)(g * 300) * 512 + f;
  float acc = 0.f;
  for (int k = 0; k < 300; ++k) acc += tg[k] * wp[(size_t)k * 512];
  ((float*)(ws + OFF_SC))[((size_t)(m * 4 + g) * 64 + b) * 512 + f] = acc;
}

// init h/c state + barrier counters
__global__ void prep_state(const float* hh, const float* hc, unsigned char* ws) {
  int t = blockIdx.x * 256 + threadIdx.x;  // 0..65535
  u16* H = (u16*)(ws + OFF_HST);
  float* C = (float*)(ws + OFF_CSTATE);
  unsigned* bar = (unsigned*)(ws + OFF_BAR);
  if (t < 64) bar[t] = 0u;
  int L = t >> 15, r = t & 32767;
  int b = r >> 9, h = r & 511;
  float hv = hh[(size_t)b * 1024 + L * 512 + h];
  float cv = hc[(size_t)b * 1024 + L * 512 + h];
  H[t] = f2bf(hv);
  C[t] = cv;
}

// ---------------- persistent kernel ----------------

__device__ __forceinline__ void gridbar(unsigned* bar) {
  __syncthreads();
  if (threadIdx.x == 0) {
    __threadfence();
    unsigned* cnt = bar;
    unsigned* gen = bar + 32;
    unsigned g0 = __hip_atomic_load(gen, __ATOMIC_RELAXED, __HIP_MEMORY_SCOPE_AGENT);
    unsigned prev = __hip_atomic_fetch_add(cnt, 1u, __ATOMIC_ACQ_REL, __HIP_MEMORY_SCOPE_AGENT);
    if (prev == 255u) {
      __hip_atomic_store(cnt, 0u, __ATOMIC_RELAXED, __HIP_MEMORY_SCOPE_AGENT);
      __hip_atomic_store(gen, g0 + 1u, __ATOMIC_RELEASE, __HIP_MEMORY_SCOPE_AGENT);
    } else {
      long spin = 0;
      while (__hip_atomic_load(gen, __ATOMIC_RELAXED, __HIP_MEMORY_SCOPE_AGENT) == g0) {
        __builtin_amdgcn_s_sleep(1);
        if (++spin > (1L << 26)) break;  // safety: never hang the harness
      }
    }
    __threadfence();
  }
  __syncthreads();
}

__global__ __launch_bounds__(256, 2) void scn_persistent(
    const float* __restrict__ inps, const float* __restrict__ bias0,
    const float* __restrict__ bias1, unsigned char* __restrict__ ws,
    float* __restrict__ out) {
  const int tid = threadIdx.x;
  const int wave = tid >> 6, lane = tid & 63, q = lane >> 4, l16 = lane & 15;
  const int bid = blockIdx.x;

  u16* P = (u16*)(ws + OFF_P);
  u16* H = (u16*)(ws + OFF_HST);
  float* C = (float*)(ws + OFF_CSTATE);
  const float* SC = (const float*)(ws + OFF_SC);
  unsigned* bar = (unsigned*)(ws + OFF_BAR);
  __shared__ float red[4][4][16][16];

  // phase-A wave-unit decode (fixed across ticks): 4m x 4g x 32ft x 2bh = 1024
  const int u = bid * 4 + wave;
  const int A_bh = u & 1, A_ft = (u >> 1) & 31, A_g = (u >> 6) & 3, A_m = u >> 8;
  // phase-B block decode: 2L x 4j x 32ht = 256
  const int B_L = bid >> 7, B_j = (bid >> 5) & 3, B_ht = bid & 31;

  for (int tau = 0; tau <= T_; ++tau) {
    // ---------------- phase A : first-stage GEMMs -> P[m] ----------------
    {
      bool act = (A_m < 2) ? (tau < T_) : (tau >= 1);
      if (act) {
        const int fcol = A_ft * 16 + l16;
        const u16* Bp = (const u16*)(ws + (size_t)A_m * WT_BYTES) +
                        (((size_t)A_g * 512 + fcol) << 9);
        const int row0 = A_bh * 32 + l16, row1 = row0 + 16;
        f32x4 acc0 = {0.f, 0.f, 0.f, 0.f}, acc1 = {0.f, 0.f, 0.f, 0.f};
        if (A_m == 0) {  // A = x_t (fp32 from inps)
          const float* x0 = inps + ((size_t)row0 * T_ + tau) * 512;
          const float* x1 = inps + ((size_t)row1 * T_ + tau) * 512;
#pragma unroll 4
          for (int kk = 0; kk < 16; ++kk) {
            int k = kk * 32 + q * 8;
            s16x8 bf = *(const s16x8*)(Bp + k);
            s16x8 a0 = cvt8(x0 + k);
            s16x8 a1 = cvt8(x1 + k);
            acc0 = mfma_bf16(a0, bf, acc0);
            acc1 = mfma_bf16(a1, bf, acc1);
          }
        } else {  // A = h0 (m=1,3) or h1 (m=2), bf16 state
          const u16* hsrc = (A_m == 2) ? (H + 32768) : H;
          const u16* h0p = hsrc + row0 * 512;
          const u16* h1p = hsrc + row1 * 512;
#pragma unroll 4
          for (int kk = 0; kk < 16; ++kk) {
            int k = kk * 32 + q * 8;
            s16x8 bf = *(const s16x8*)(Bp + k);
            s16x8 a0 = *(const s16x8*)(h0p + k);
            s16x8 a1 = *(const s16x8*)(h1p + k);
            acc0 = mfma_bf16(a0, bf, acc0);
            acc1 = mfma_bf16(a1, bf, acc1);
          }
        }
        const size_t mg = (size_t)(A_m * 4 + A_g) * 64;
        const float* sc = SC + (mg << 9) + fcol;
        u16* Pp = P + (mg << 9) + fcol;
#pragma unroll
        for (int r = 0; r < 4; ++r) {
          int b0r = A_bh * 32 + q * 4 + r;
          Pp[(size_t)b0r << 9] = f2bf(acc0[r] * sc[(size_t)b0r << 9]);
          int b1r = b0r + 16;
          Pp[(size_t)b1r << 9] = f2bf(acc1[r] * sc[(size_t)b1r << 9]);
        }
      }
      gridbar(bar);
    }
    // ---------------- phase B : second-stage GEMMs + gate epilogue ----------------
    {
      bool act = (B_L == 0) ? (tau < T_) : (tau >= 1);
      if (act) {
        const int xp = (wave < 2) ? 0 : 1;        // 0 = x-path, 1 = h-path
        const int fbase = (wave & 1) * 256;       // K-quarter within the path
        const int Pidx = (B_L == 0) ? xp : (3 - xp);  // L0: P0/P1 ; L1: P3/P2
        const u16* Pm = P + ((size_t)Pidx << 17);
        const u16* Wt = (const u16*)(ws + (size_t)(4 + B_L * 2 + xp) * WT_BYTES);
        f32x4 acc[4] = {{0.f,0.f,0.f,0.f},{0.f,0.f,0.f,0.f},
                        {0.f,0.f,0.f,0.f},{0.f,0.f,0.f,0.f}};
#pragma unroll 2
        for (int kk = 0; kk < 8; ++kk) {
          int k = fbase + kk * 32 + q * 8;
#pragma unroll
          for (int g = 0; g < 4; ++g) {
            s16x8 af = *(const s16x8*)(Pm + ((size_t)((g * 64 + B_j * 16 + l16)) << 9) + k);
            s16x8 bf = *(const s16x8*)(Wt + ((size_t)((g * 512 + B_ht * 16 + l16)) << 9) + k);
            acc[g] = mfma_bf16(af, bf, acc[g]);
          }
        }
#pragma unroll
        for (int g = 0; g < 4; ++g)
#pragma unroll
          for (int r = 0; r < 4; ++r)
            red[wave][g][q * 4 + r][l16] = acc[g][r];
      }
      __syncthreads();
      if (act) {
        const int row = tid >> 4, col = tid & 15;
        const int b = B_j * 16 + row, h = B_ht * 16 + col;
        const float* bias = (B_L == 0) ? bias0 : bias1;
        float s[4];
#pragma unroll
        for (int g = 0; g < 4; ++g) {
          float v = bias[g * 512 + h];
          v += red[0][g][row][col] + red[1][g][row][col] +
               red[2][g][row][col] + red[3][g][row][col];
          s[g] = 1.0f / (1.0f + __expf(-v));
        }
        float* cp = C + B_L * 32768 + b * 512 + h;
        float cprev = *cp;
        float cn = s[0] * s[3] + s[1] * cprev;
        *cp = cn;
        float hn = s[2] * tanhf(cn);
        H[B_L * 32768 + b * 512 + h] = f2bf(hn);
        if (B_L == 1) {
          out[(((size_t)b * T_ + (tau - 1)) << 9) + h] = hn;  // out[b][t][h], t=tau-1
          if (tau == T_) {
            out[OUT_HST + b * 1024 + 512 + h] = hn;
            out[OUT_CST + b * 1024 + 512 + h] = cn;
          }
        } else if (tau == T_ - 1) {
          out[OUT_HST + b * 1024 + h] = hn;
          out[OUT_CST + b * 1024 + h] = cn;
        }
      }
      gridbar(bar);
    }
  }
}

// ---------------- host launch ----------------

extern "C" void kernel_launch(void* const* d_in, const int* in_sizes, int n_in,
                              void* d_out, int out_size, void* d_ws, size_t ws_size,
                              hipStream_t stream) {
  const float* inps = (const float*)d_in[0];
  const float* hh   = (const float*)d_in[1];
  const float* hc   = (const float*)d_in[2];
  const float* tag  = (const float*)d_in[3];
  const float* Wa0 = (const float*)d_in[4];
  const float* Wb0 = (const float*)d_in[5];
  const float* Wc0 = (const float*)d_in[6];
  const float* Ua0 = (const float*)d_in[7];
  const float* Ub0 = (const float*)d_in[8];
  const float* Uc0 = (const float*)d_in[9];
  const float* b0  = (const float*)d_in[10];
  const float* Wa1 = (const float*)d_in[11];
  const float* Wb1 = (const float*)d_in[12];
  const float* Wc1 = (const float*)d_in[13];
  const float* Ua1 = (const float*)d_in[14];
  const float* Ub1 = (const float*)d_in[15];
  const float* Uc1 = (const float*)d_in[16];
  const float* b1  = (const float*)d_in[17];
  unsigned char* ws = (unsigned char*)d_ws;

  // transposed-weight slot order: [0]=Wc0 [1]=Uc0 [2]=Uc1 [3]=Wc1 (phase A)
  //                               [4]=Wa0 [5]=Ua0 [6]=Wa1 [7]=Ua1 (phase B)
  SrcPtrs sp;
  sp.p[0] = Wc0; sp.p[1] = Uc0; sp.p[2] = Uc1; sp.p[3] = Wc1;
  sp.p[4] = Wa0; sp.p[5] = Ua0; sp.p[6] = Wa1; sp.p[7] = Ua1;

  prep_transpose<<<dim3(2048), dim3(256), 0, stream>>>(sp, ws);
  prep_scales<<<dim3(2048), dim3(256), 0, stream>>>(tag, Wb0, Ub0, Ub1, Wb1, ws);
  prep_state<<<dim3(256), dim3(256), 0, stream>>>(hh, hc, ws);
  scn_persistent<<<dim3(256), dim3(256), 0, stream>>>(inps, b0, b1, ws, (float*)d_out);
}